// Round 2
// baseline (280.034 us; speedup 1.0000x reference)
//
#include <hip/hip_runtime.h>

// SNN forward: [merged preps] -> [GEMM1+scan1 fused, 128x128, DIRECT-TO-REG
// fragment loads, ZERO K-loop barriers, 512 thr / 8 waves] -> GEMM2
// (direct-reg, no LDS, no barriers) -> scan2.
// f16 split-2: W = hi + lo (both f16), residual ~2^-24 => fp32-grade MFMA.
// R16 insight: mfma_16x16x32 A/B fragments are per-lane CONTIGUOUS 16B in
// K-major global layout -> load global->VGPR directly (4 kq-lanes = one 64B
// line). Kills all staging barriers (R15 showed zero-conflict LDS + counted
// vmcnt changed nothing => kernel was barrier-lockstep-bound, not BW-bound).
// LDS now holds only yb (67.6KB, 2 blocks/CU). 2 barriers/chunk: scan(c) by
// waves 0-1 overlaps GEMM(c+1) by waves 2-7.

#define NN 64
#define II 256
#define HH 1024
#define OO 18
#define TT 500

#define D_SR 0.9048374180359595f   // exp(-1/10)
#define C_SR 0.27182818284590454f  // e/10
#define D_RF 0.36787944117144233f  // exp(-1)
#define C_RF 2.718281828459045f    // e
#define THETA 10.0f
#define REFS (-20.0f)

typedef _Float16 f16;
typedef _Float16 f16x8 __attribute__((ext_vector_type(8)));
typedef float f32x4 __attribute__((ext_vector_type(4)));

// ---------------- merged prep: X transpose + W1 hi/lo + W2 hi/lo ------------
// grid 3200: [0,2048) prep_x tiles, [2048,3072) W1, [3072,3200) W2.
__launch_bounds__(256)
__global__ void prep_all(const float* __restrict__ X, const float* __restrict__ W1,
                         const float* __restrict__ W2, f16* __restrict__ Xb,
                         f16* __restrict__ W1h, f16* __restrict__ W1l,
                         f16* __restrict__ W2h, f16* __restrict__ W2l) {
    __shared__ float tile[64][65];
    const int b = blockIdx.x;
    const int tid = threadIdx.x;

    if (b < 2048) {
        const int t0 = (b & 7) * 64, i0 = ((b >> 3) & 3) * 64, n = b >> 5;
        const int tx = tid & 63, q = tid >> 6;
        const float* Xn = X + (size_t)n * II * TT;
#pragma unroll 4
        for (int j = 0; j < 16; ++j) {
            int il = j * 4 + q;
            int t = t0 + tx;
            tile[il][tx] = (t < TT) ? Xn[(size_t)(i0 + il) * TT + t] : 0.f;
        }
        __syncthreads();
#pragma unroll 4
        for (int j = 0; j < 16; ++j) {
            int tl = j * 4 + q;
            int t = t0 + tl;
            if (t < TT)
                Xb[((size_t)n * TT + t) * II + i0 + tx] = (f16)tile[tx][tl];
        }
    } else if (b < 3072) {
        int idx = (b - 2048) * 256 + tid;
        float w = W1[idx];
        f16 h = (f16)w;
        f16 l = (f16)(w - (float)h);
        W1h[idx] = h;
        W1l[idx] = l;
    } else {
        int idx = (b - 3072) * 256 + tid;
        int o = idx >> 10;
        float w = (o < OO) ? W2[idx] : 0.f;
        f16 h = (f16)w;
        f16 l = (f16)(w - (float)h);
        W2h[idx] = h;
        W2l[idx] = l;
    }
}

// ---------------- FUSED layer 1: 128x128 tile, direct-reg, 8 waves ---------
// grid (8, 64), 512 thr. Per block: 4 t-chunks of 128.
// Wave layout 2m x 4n: wave w covers rows wm*64+[0,64), cols wn*32+[0,32).
// No LDS staging: per kk each lane loads its own 16B A/B fragments from
// global (L1/L2-served reuse). Barriers only around the yb epilogue/scan.
__launch_bounds__(512, 4)
__global__ void gemm1_scan1(const f16* __restrict__ Xb, const f16* __restrict__ Wh,
                            const f16* __restrict__ Wl, f16* __restrict__ S1) {
    __shared__ float yb[128 * 132];  // 67,584 B

    const int tid = threadIdx.x;
    const int wave = tid >> 6, lane = tid & 63;

    // XCD swizzle: the 8 h-tiles of one n share an XCD
    const int f = blockIdx.y * 8 + blockIdx.x;
    const int x = f & 7, g = f >> 3;
    const int n = x * 8 + (g & 7);
    const int ht = g >> 3;
    const int h0g = ht * 128;

    const int wm = wave & 1, wn = wave >> 1;   // 2m x 4n
    const int fr = lane & 15, kq = lane >> 4;

    const f16* gA = Xb + (size_t)n * TT * II;
    // B row element-offsets (constant across chunks)
    size_t bo0 = (size_t)(h0g + wn * 32 + fr) * II + kq * 8;
    size_t bo1 = bo0 + (size_t)16 * II;

    float p1 = 0.f, a1 = 0.f, p2 = 0.f, a2 = 0.f;  // scan state (tid<128)

    for (int c = 0; c < 4; ++c) {
        const int t0 = c * 128;
        const int TCe = (TT - t0 < 128) ? (TT - t0) : 128;

        // A row indices for this chunk (clamped for the 500-tail; duplicate
        // rows feed acc rows the scan never reads)
        size_t ao[4];
#pragma unroll
        for (int i = 0; i < 4; ++i) {
            int r = t0 + wm * 64 + i * 16 + fr;
            if (r > TT - 1) r = TT - 1;
            ao[i] = (size_t)r * II + kq * 8;
        }

        f32x4 acc[4][2] = {};
#pragma unroll
        for (int kk = 0; kk < 8; ++kk) {
            const int ko = kk * 32;
            f16x8 av[4], bh[2], bl[2];
#pragma unroll
            for (int i = 0; i < 4; ++i)
                av[i] = *(const f16x8*)(gA + ao[i] + ko);
            bh[0] = *(const f16x8*)(Wh + bo0 + ko);
            bh[1] = *(const f16x8*)(Wh + bo1 + ko);
            bl[0] = *(const f16x8*)(Wl + bo0 + ko);
            bl[1] = *(const f16x8*)(Wl + bo1 + ko);
#pragma unroll
            for (int i = 0; i < 4; ++i)
#pragma unroll
                for (int j = 0; j < 2; ++j) {
                    acc[i][j] = __builtin_amdgcn_mfma_f32_16x16x32_f16(av[i], bh[j], acc[i][j], 0, 0, 0);
                    acc[i][j] = __builtin_amdgcn_mfma_f32_16x16x32_f16(av[i], bl[j], acc[i][j], 0, 0, 0);
                }
        }

        __syncthreads();  // previous chunk's scan finished reading yb

        // epilogue: acc -> yb (t-major, stride 132)
#pragma unroll
        for (int i = 0; i < 4; ++i)
#pragma unroll
            for (int j = 0; j < 2; ++j) {
                int tr = wm * 64 + i * 16 + kq * 4;
                int hc = wn * 32 + j * 16 + fr;
#pragma unroll
                for (int r = 0; r < 4; ++r)
                    yb[(tr + r) * 132 + hc] = acc[i][j][r];
            }
        __syncthreads();  // yb complete; waves 2-7 roll into next chunk's GEMM

        // sequential scan (waves 0-1); 8-deep ring; spikes -> global directly
        if (tid < 128) {
            f16* sq = S1 + ((size_t)n * TT + t0) * HH + h0g + tid;
            float rb_[8];
#pragma unroll
            for (int j = 0; j < 8; ++j) rb_[j] = yb[j * 132 + tid];
            int t = 0;
            for (; t + 8 <= TCe; t += 8) {
#pragma unroll
                for (int j = 0; j < 8; ++j) {
                    float xv = rb_[j];
                    int tn = t + j + 8;
                    rb_[j] = (tn < TCe) ? yb[tn * 132 + tid] : 0.f;
                    a1 = D_SR * (a1 + p1);
                    p1 = D_SR * p1 + xv;
                    float ut = C_SR * a1;
                    a2 = D_RF * (a2 + p2);
                    float u = ut + C_RF * a2;
                    float s = (u >= THETA) ? 1.0f : 0.0f;
                    p2 = D_RF * p2 + REFS * s;
                    sq[(size_t)(t + j) * HH] = (f16)s;
                }
            }
            int rem = TCe - t;
#pragma unroll
            for (int j = 0; j < 8; ++j) {
                if (j < rem) {
                    float xv = rb_[j];
                    a1 = D_SR * (a1 + p1);
                    p1 = D_SR * p1 + xv;
                    float ut = C_SR * a1;
                    a2 = D_RF * (a2 + p2);
                    float u = ut + C_RF * a2;
                    float s = (u >= THETA) ? 1.0f : 0.0f;
                    p2 = D_RF * p2 + REFS * s;
                    sq[(size_t)(t + j) * HH] = (f16)s;
                }
            }
        }
        // no barrier here: next chunk's pre-epilogue barrier protects yb
    }
}

// ---------------- GEMM2 (MFMA, split-f16, direct-reg, no LDS) ---------------
// grid 500; 256 thr / 4 waves; tile 64 m x 32 o; wave = 16m x 32o (no A dup).
// W2 hi/lo = 128 KB total -> L1/L2-resident; S1 streams from HBM.
__launch_bounds__(256)
__global__ void gemm2_mfma(const f16* __restrict__ S1, const f16* __restrict__ W2h,
                           const f16* __restrict__ W2l, float* __restrict__ Y2) {
    const int tid = threadIdx.x;
    const int wave = tid >> 6, lane = tid & 63;
    const int m0 = blockIdx.x * 64;
    const int fr = lane & 15, kq = lane >> 4;

    const f16* gA = S1 + (size_t)(m0 + wave * 16 + fr) * HH + kq * 8;
    size_t bo0 = (size_t)fr * HH + kq * 8;
    size_t bo1 = bo0 + (size_t)16 * HH;

    f32x4 acc[2] = {};
#pragma unroll 8
    for (int kk = 0; kk < HH / 32; ++kk) {
        const int ko = kk * 32;
        f16x8 a, bh[2], bl[2];
        a = *(const f16x8*)(gA + ko);
        bh[0] = *(const f16x8*)(W2h + bo0 + ko);
        bh[1] = *(const f16x8*)(W2h + bo1 + ko);
        bl[0] = *(const f16x8*)(W2l + bo0 + ko);
        bl[1] = *(const f16x8*)(W2l + bo1 + ko);
#pragma unroll
        for (int j = 0; j < 2; ++j) {
            acc[j] = __builtin_amdgcn_mfma_f32_16x16x32_f16(a, bh[j], acc[j], 0, 0, 0);
            acc[j] = __builtin_amdgcn_mfma_f32_16x16x32_f16(a, bl[j], acc[j], 0, 0, 0);
        }
    }

#pragma unroll
    for (int j = 0; j < 2; ++j) {
        int rbase = m0 + wave * 16 + kq * 4;
        int cc = j * 16 + fr;
        float* p = Y2 + (size_t)rbase * 32 + cc;
#pragma unroll
        for (int r = 0; r < 4; ++r)
            p[(size_t)r * 32] = acc[j][r];
    }
}

// ---------------- scan2: single-phase LDS, static-index ring ----------------
__launch_bounds__(256)
__global__ void scan2_k(const float* __restrict__ Y2, float* __restrict__ Out) {
    __shared__ float yc[TT * 32];    // 64,000 B
    __shared__ float sb[OO * TT];    // 36,000 B
    const int n = blockIdx.x, tid = threadIdx.x;

    const float4* src = (const float4*)(Y2 + (size_t)n * TT * 32);
    float4* dst = (float4*)yc;
    for (int i = tid; i < TT * 8; i += 256) dst[i] = src[i];
    __syncthreads();

    if (tid < 32) {
        float p1 = 0.f, a1 = 0.f, p2 = 0.f, a2 = 0.f;
        float rb_[8];
#pragma unroll
        for (int j = 0; j < 8; ++j) rb_[j] = yc[j * 32 + tid];
        int t = 0;
        for (; t + 8 <= TT; t += 8) {
#pragma unroll
            for (int j = 0; j < 8; ++j) {
                float xv = rb_[j];
                int tn = t + j + 8;
                rb_[j] = (tn < TT) ? yc[tn * 32 + tid] : 0.f;
                a1 = D_SR * (a1 + p1);
                p1 = D_SR * p1 + xv;
                float ut = C_SR * a1;
                a2 = D_RF * (a2 + p2);
                float u = ut + C_RF * a2;
                float s = (u >= THETA) ? 1.0f : 0.0f;
                p2 = D_RF * p2 + REFS * s;
                if (tid < OO) sb[tid * TT + t + j] = s;
            }
        }
#pragma unroll
        for (int j = 0; j < 8; ++j) {
            if (t + j < TT) {
                float xv = rb_[j];
                a1 = D_SR * (a1 + p1);
                p1 = D_SR * p1 + xv;
                float ut = C_SR * a1;
                a2 = D_RF * (a2 + p2);
                float u = ut + C_RF * a2;
                float s = (u >= THETA) ? 1.0f : 0.0f;
                p2 = D_RF * p2 + REFS * s;
                if (tid < OO) sb[tid * TT + t + j] = s;
            }
        }
    }
    __syncthreads();

    float* on = Out + (size_t)n * OO * TT;
    for (int e = tid; e < OO * TT; e += 256) on[e] = sb[e];
}

extern "C" void kernel_launch(void* const* d_in, const int* in_sizes, int n_in,
                              void* d_out, int out_size, void* d_ws, size_t ws_size,
                              hipStream_t stream) {
    const float* X  = (const float*)d_in[0];
    const float* W1 = (const float*)d_in[1];
    const float* W2 = (const float*)d_in[2];
    float* out = (float*)d_out;

    const size_t s_s1 = (size_t)NN * TT * HH * 2;   // 65,536,000
    const size_t s_Xb = (size_t)NN * TT * II * 2;   // 16,384,000
    const size_t s_W  = (size_t)HH * II * 2;        //    524,288 (x2)
    const size_t s_W2 = (size_t)32 * HH * 2;        //     65,536 (x2)
    // + y2 4,096,000 => ~87 MB total

    char* w = (char*)d_ws;
    f16*   s1b = (f16*)w;  w += s_s1;
    f16*   Xb  = (f16*)w;  w += s_Xb;
    f16*   W1h = (f16*)w;  w += s_W;
    f16*   W1l = (f16*)w;  w += s_W;
    f16*   W2h = (f16*)w;  w += s_W2;
    f16*   W2l = (f16*)w;  w += s_W2;
    float* y2  = (float*)w;

    prep_all<<<3200, 256, 0, stream>>>(X, W1, W2, Xb, W1h, W1l, W2h, W2l);

    gemm1_scan1<<<dim3(8, NN), 512, 0, stream>>>(Xb, W1h, W1l, s1b);

    gemm2_mfma<<<(NN * TT) / 64, 256, 0, stream>>>(s1b, W2h, W2l, y2);
    scan2_k<<<NN, 256, 0, stream>>>(y2, out);
}

// Round 3
// 201.098 us; speedup vs baseline: 1.3925x; 1.3925x over previous
//
#include <hip/hip_runtime.h>

// SNN forward: [merged preps] -> [GEMM1+scan1 fused, 128x128, INTERLEAVED
// scan: 16 scan-steps of chunk c-1 inside each kk phase of chunk c; two
// alternating 67.6KB LDS regions (staging dbuf of chunk c aliases the
// already-consumed yb region); spikes bit-packed in LDS, flushed coalesced]
// -> GEMM2 (ring-3 LDS, R1 version) -> scan2.
// f16 split-2: W = hi + lo (both f16), residual ~2^-24 => fp32-grade MFMA.
// R17 lessons: R2 direct-to-reg = FETCH x10 (write-stream evicts L2 reuse;
// LDS staging is volume-essential). R0==R15 (conflicts/vmcnt irrelevant) =>
// binding cost was scan/GEMM lockstep serialization -> interleave inside
// the per-kk barriers; 1 block/CU accepted (idle time, not occupancy, bound).

#define NN 64
#define II 256
#define HH 1024
#define OO 18
#define TT 500

#define D_SR 0.9048374180359595f   // exp(-1/10)
#define C_SR 0.27182818284590454f  // e/10
#define D_RF 0.36787944117144233f  // exp(-1)
#define C_RF 2.718281828459045f    // e
#define THETA 10.0f
#define REFS (-20.0f)

typedef _Float16 f16;
typedef _Float16 f16x8 __attribute__((ext_vector_type(8)));
typedef float f32x4 __attribute__((ext_vector_type(4)));
typedef unsigned int uint;

__device__ __forceinline__ void gl2lds16(const void* g, void* l) {
    __builtin_amdgcn_global_load_lds(
        (const __attribute__((address_space(1))) void*)g,
        (__attribute__((address_space(3))) void*)l, 16, 0, 0);
}

// ---------------- merged prep: X transpose + W1 hi/lo + W2 hi/lo ------------
// grid 3200: [0,2048) prep_x tiles, [2048,3072) W1, [3072,3200) W2.
__launch_bounds__(256)
__global__ void prep_all(const float* __restrict__ X, const float* __restrict__ W1,
                         const float* __restrict__ W2, f16* __restrict__ Xb,
                         f16* __restrict__ W1h, f16* __restrict__ W1l,
                         f16* __restrict__ W2h, f16* __restrict__ W2l) {
    __shared__ float tile[64][65];
    const int b = blockIdx.x;
    const int tid = threadIdx.x;

    if (b < 2048) {
        const int t0 = (b & 7) * 64, i0 = ((b >> 3) & 3) * 64, n = b >> 5;
        const int tx = tid & 63, q = tid >> 6;
        const float* Xn = X + (size_t)n * II * TT;
#pragma unroll 4
        for (int j = 0; j < 16; ++j) {
            int il = j * 4 + q;
            int t = t0 + tx;
            tile[il][tx] = (t < TT) ? Xn[(size_t)(i0 + il) * TT + t] : 0.f;
        }
        __syncthreads();
#pragma unroll 4
        for (int j = 0; j < 16; ++j) {
            int tl = j * 4 + q;
            int t = t0 + tl;
            if (t < TT)
                Xb[((size_t)n * TT + t) * II + i0 + tx] = (f16)tile[tx][tl];
        }
    } else if (b < 3072) {
        int idx = (b - 2048) * 256 + tid;
        float w = W1[idx];
        f16 h = (f16)w;
        f16 l = (f16)(w - (float)h);
        W1h[idx] = h;
        W1l[idx] = l;
    } else {
        int idx = (b - 3072) * 256 + tid;
        int o = idx >> 10;
        float w = (o < OO) ? W2[idx] : 0.f;
        f16 h = (f16)w;
        f16 l = (f16)(w - (float)h);
        W2h[idx] = h;
        W2l[idx] = l;
    }
}

// ---------------- FUSED layer 1: 128x128 tile, interleaved scan -------------
// grid (8, 64), 512 thr / 8 waves. Per block: 4 t-chunks of 128.
// Wave layout 2m x 4n. Staging: wave w stages rows [w*16, w*16+16).
// Regions: smem_[c&1] = chunk c's {staging dbuf -> yb}; smem_[(c+1)&1] holds
// yb(c-1), read by the interleaved scan. sbits: 128-bit spike mask per h.
__launch_bounds__(512, 2)
__global__ void gemm1_scan1(const f16* __restrict__ Xb, const f16* __restrict__ Wh,
                            const f16* __restrict__ Wl, f16* __restrict__ S1) {
    __shared__ __align__(16) char smem_[2][67584];  // 135,168 B
    __shared__ uint sbits[4][128];                  //   2,048 B

    const int tid = threadIdx.x;
    const int wave = tid >> 6, lane = tid & 63;

    // XCD swizzle: the 8 h-tiles of one n share an XCD
    const int f = blockIdx.y * 8 + blockIdx.x;
    const int x = f & 7, g = f >> 3;
    const int n = x * 8 + (g & 7);
    const int ht = g >> 3;
    const int h0g = ht * 128;

    const int rbl = wave * 16 + (lane >> 2);   // staged row 0..127
    // swizzled source slot: (lane&3) ^ sigma(row), sigma(row)=(lane>>3)&3
    const int koff = (((lane & 3) ^ ((lane >> 3) & 3))) * 8;
    const f16* gBh0 = Wh + (size_t)(h0g + rbl) * II + koff;
    const f16* gBl0 = Wl + (size_t)(h0g + rbl) * II + koff;

    const int wm = wave & 1, wn = wave >> 1;   // 2m x 4n
    const int fr = lane & 15, kq = lane >> 4;
    const int kz = (kq ^ ((fr >> 1) & 3)) * 8;  // swizzled read slot (f16 idx)

    float p1 = 0.f, a1 = 0.f, p2 = 0.f, a2 = 0.f;  // scan state (tid<128)

    auto mkA = [&](int c) -> const f16* {
        int r = c * 128 + rbl;
        if (r > TT - 1) r = TT - 1;  // clamped dup rows; scan never reads them
        return Xb + ((size_t)n * TT + r) * II + koff;
    };
    auto stage = [&](const f16* gA0c, int kk2, int b, char* regp) {
        f16* As_b = (f16*)(regp + b * 24576);
        const int ko = kk2 * 32;
        gl2lds16(gA0c + ko, As_b + wave * 512);
        gl2lds16(gBh0 + ko, As_b + 4096 + wave * 512);
        gl2lds16(gBl0 + ko, As_b + 8192 + wave * 512);
    };
    // coalesced spike flush: 128t x 128h f16 from the bitmask (2048 x 16B)
    auto flush = [&](int tc0, int TC) {
#pragma unroll
        for (int v = 0; v < 4; ++v) {
            int slot = v * 512 + tid;
            int t = slot >> 4, h8 = slot & 15;
            if (t < TC) {
                int wsel = t >> 5, bit = t & 31;
                f16x8 vv;
#pragma unroll
                for (int e = 0; e < 8; ++e) {
                    uint wv = sbits[wsel][h8 * 8 + e];
                    vv[e] = (f16)(float)((wv >> bit) & 1u);
                }
                *(f16x8*)(S1 + ((size_t)n * TT + tc0 + t) * HH + h0g + h8 * 8) = vv;
            }
        }
    };

    const f16* gA0c = mkA(0);
    stage(gA0c, 0, 0, smem_[0]);

    for (int c = 0; c < 4; ++c) {
        char* reg = smem_[c & 1];
        const float* ybp = (const float*)smem_[(c + 1) & 1];  // yb(c-1)
        float* yb = (float*)reg;

        f32x4 acc[4][2] = {};
        uint tmpw = 0;
#pragma unroll
        for (int kk = 0; kk < 8; ++kk) {
            __syncthreads();                 // buf[kk&1] DMA drained + visible
            if (kk < 7) stage(gA0c, kk + 1, (kk + 1) & 1, reg);

            const f16* As_b = (const f16*)(reg + (kk & 1) * 24576);
            const f16* Bh_b = As_b + 4096;
            const f16* Bl_b = As_b + 8192;

            f16x8 av[4], bhv[2], blv[2];
#pragma unroll
            for (int i = 0; i < 4; ++i)
                av[i] = *(const f16x8*)(As_b + (wm * 64 + i * 16 + fr) * 32 + kz);
#pragma unroll
            for (int j = 0; j < 2; ++j) {
                bhv[j] = *(const f16x8*)(Bh_b + (wn * 32 + j * 16 + fr) * 32 + kz);
                blv[j] = *(const f16x8*)(Bl_b + (wn * 32 + j * 16 + fr) * 32 + kz);
            }
#pragma unroll
            for (int i = 0; i < 4; ++i)
#pragma unroll
                for (int j = 0; j < 2; ++j) {
                    acc[i][j] = __builtin_amdgcn_mfma_f32_16x16x32_f16(av[i], bhv[j], acc[i][j], 0, 0, 0);
                    acc[i][j] = __builtin_amdgcn_mfma_f32_16x16x32_f16(av[i], blv[j], acc[i][j], 0, 0, 0);
                }

            // interleaved scan: 16 steps of chunk c-1 (VALU pipe, hidden
            // under the other waves' barrier slack + MFMA)
            if (c > 0 && tid < 128) {
                float xv[16];
#pragma unroll
                for (int j = 0; j < 16; ++j)
                    xv[j] = ybp[(kk * 16 + j) * 132 + tid];
                uint mbits = 0;
#pragma unroll
                for (int j = 0; j < 16; ++j) {
                    a1 = D_SR * (a1 + p1);
                    p1 = D_SR * p1 + xv[j];
                    float ut = C_SR * a1;
                    a2 = D_RF * (a2 + p2);
                    float u = ut + C_RF * a2;
                    float s = (u >= THETA) ? 1.0f : 0.0f;
                    p2 = D_RF * p2 + REFS * s;
                    mbits |= (u >= THETA ? 1u : 0u) << j;
                }
                if ((kk & 1) == 0) tmpw = mbits;
                else sbits[kk >> 1][tid] = tmpw | (mbits << 16);
            }
        }
        __syncthreads();  // frag reads + sbits writes done

        // prefetch next chunk's first staging buffer (its region's yb was
        // consumed by the scan that just finished)
        if (c < 3) {
            gA0c = mkA(c + 1);
            stage(gA0c, 0, 0, smem_[(c + 1) & 1]);
        }
        // flush chunk c-1 spikes (coalesced 16B stores)
        if (c > 0) flush((c - 1) * 128, 128);

        // epilogue: acc -> yb (t-major, stride 132) over the staging bufs
#pragma unroll
        for (int i = 0; i < 4; ++i)
#pragma unroll
            for (int j = 0; j < 2; ++j) {
                int tr = wm * 64 + i * 16 + kq * 4;
                int hc = wn * 32 + j * 16 + fr;
#pragma unroll
                for (int r = 0; r < 4; ++r)
                    yb[(tr + r) * 132 + hc] = acc[i][j][r];
            }
        __syncthreads();  // yb(c) complete; scan(c) runs during chunk c+1
    }

    // tail: scan chunk 3 (t = 384..499, 116 steps), yb(3) in smem_[1]
    {
        const float* ybp = (const float*)smem_[1];
        if (tid < 128) {
            uint tmpw = 0;
#pragma unroll
            for (int kk = 0; kk < 8; ++kk) {
                uint mbits = 0;
#pragma unroll
                for (int j = 0; j < 16; ++j) {
                    int t = kk * 16 + j;
                    if (t < TT - 384) {
                        float xv = ybp[t * 132 + tid];
                        a1 = D_SR * (a1 + p1);
                        p1 = D_SR * p1 + xv;
                        float ut = C_SR * a1;
                        a2 = D_RF * (a2 + p2);
                        float u = ut + C_RF * a2;
                        float s = (u >= THETA) ? 1.0f : 0.0f;
                        p2 = D_RF * p2 + REFS * s;
                        mbits |= (u >= THETA ? 1u : 0u) << j;
                    }
                }
                if ((kk & 1) == 0) tmpw = mbits;
                else sbits[kk >> 1][tid] = tmpw | (mbits << 16);
            }
        }
        __syncthreads();
        flush(384, TT - 384);
    }
}

// ---------------- GEMM2 (MFMA, split-f16, ring-3, 64-row tiles) -------------
// grid 500; 256 thr; tile 64 m x 32 o; K=1024, BK=32, counted-vmcnt pipeline.
__launch_bounds__(256)
__global__ void gemm2_mfma(const f16* __restrict__ S1, const f16* __restrict__ W2h,
                           const f16* __restrict__ W2l, float* __restrict__ Y2) {
    __shared__ __align__(16) f16 As[3][64 * 32];  // 3 x 4 KB
    __shared__ __align__(16) f16 Bh[3][32 * 32];  // 3 x 2 KB
    __shared__ __align__(16) f16 Bl[3][32 * 32];  // 3 x 2 KB

    const int tid = threadIdx.x;
    const int wave = tid >> 6, lane = tid & 63;
    const int m0 = blockIdx.x * 64;
    const int fr = lane & 15, kq = lane >> 4;
    const int koff = (((lane & 3) ^ ((lane >> 3) & 3))) * 8;  // swizzled src slot
    const int kz = (kq ^ ((fr >> 1) & 3)) * 8;                // swizzled read slot

    const f16* gA = S1 + (size_t)(m0 + wave * 16 + (lane >> 2)) * HH + koff;
    const f16* gB = (wave < 2 ? W2h : W2l) + (size_t)((wave & 1) * 16 + (lane >> 2)) * HH + koff;

    auto stage = [&](int kk2, int b) {
        const int ko = kk2 * 32;
        gl2lds16(gA + ko, &As[b][wave * 512]);
        gl2lds16(gB + ko, (wave < 2 ? &Bh[b][0] : &Bl[b][0]) + (wave & 1) * 512);
    };

    stage(0, 0);
    stage(1, 1);

    f32x4 acc[2] = {};
#pragma unroll
    for (int kk = 0; kk < HH / 32; ++kk) {
        if (kk < HH / 32 - 1) asm volatile("s_waitcnt vmcnt(2)" ::: "memory");
        else                  asm volatile("s_waitcnt vmcnt(0)" ::: "memory");
        __builtin_amdgcn_s_barrier();
        __builtin_amdgcn_sched_barrier(0);
        if (kk < HH / 32 - 2) stage(kk + 2, (kk + 2) % 3);
        const int b = kk % 3;

        f16x8 a, bh[2], bl[2];
        a = *(const f16x8*)(&As[b][(wave * 16 + fr) * 32 + kz]);
#pragma unroll
        for (int j = 0; j < 2; ++j) {
            bh[j] = *(const f16x8*)(&Bh[b][(j * 16 + fr) * 32 + kz]);
            bl[j] = *(const f16x8*)(&Bl[b][(j * 16 + fr) * 32 + kz]);
        }
        __builtin_amdgcn_s_setprio(1);
#pragma unroll
        for (int j = 0; j < 2; ++j) {
            acc[j] = __builtin_amdgcn_mfma_f32_16x16x32_f16(a, bh[j], acc[j], 0, 0, 0);
            acc[j] = __builtin_amdgcn_mfma_f32_16x16x32_f16(a, bl[j], acc[j], 0, 0, 0);
        }
        __builtin_amdgcn_s_setprio(0);
    }

#pragma unroll
    for (int j = 0; j < 2; ++j) {
        int rbase = m0 + wave * 16 + kq * 4;
        int cc = j * 16 + fr;
        float* p = Y2 + (size_t)rbase * 32 + cc;
#pragma unroll
        for (int r = 0; r < 4; ++r)
            p[(size_t)r * 32] = acc[j][r];
    }
}

// ---------------- scan2: single-phase LDS, static-index ring ----------------
__launch_bounds__(256)
__global__ void scan2_k(const float* __restrict__ Y2, float* __restrict__ Out) {
    __shared__ float yc[TT * 32];    // 64,000 B
    __shared__ float sb[OO * TT];    // 36,000 B
    const int n = blockIdx.x, tid = threadIdx.x;

    const float4* src = (const float4*)(Y2 + (size_t)n * TT * 32);
    float4* dst = (float4*)yc;
    for (int i = tid; i < TT * 8; i += 256) dst[i] = src[i];
    __syncthreads();

    if (tid < 32) {
        float p1 = 0.f, a1 = 0.f, p2 = 0.f, a2 = 0.f;
        float rb_[8];
#pragma unroll
        for (int j = 0; j < 8; ++j) rb_[j] = yc[j * 32 + tid];
        int t = 0;
        for (; t + 8 <= TT; t += 8) {
#pragma unroll
            for (int j = 0; j < 8; ++j) {
                float xv = rb_[j];
                int tn = t + j + 8;
                rb_[j] = (tn < TT) ? yc[tn * 32 + tid] : 0.f;
                a1 = D_SR * (a1 + p1);
                p1 = D_SR * p1 + xv;
                float ut = C_SR * a1;
                a2 = D_RF * (a2 + p2);
                float u = ut + C_RF * a2;
                float s = (u >= THETA) ? 1.0f : 0.0f;
                p2 = D_RF * p2 + REFS * s;
                if (tid < OO) sb[tid * TT + t + j] = s;
            }
        }
#pragma unroll
        for (int j = 0; j < 8; ++j) {
            if (t + j < TT) {
                float xv = rb_[j];
                a1 = D_SR * (a1 + p1);
                p1 = D_SR * p1 + xv;
                float ut = C_SR * a1;
                a2 = D_RF * (a2 + p2);
                float u = ut + C_RF * a2;
                float s = (u >= THETA) ? 1.0f : 0.0f;
                p2 = D_RF * p2 + REFS * s;
                if (tid < OO) sb[tid * TT + t + j] = s;
            }
        }
    }
    __syncthreads();

    float* on = Out + (size_t)n * OO * TT;
    for (int e = tid; e < OO * TT; e += 256) on[e] = sb[e];
}

extern "C" void kernel_launch(void* const* d_in, const int* in_sizes, int n_in,
                              void* d_out, int out_size, void* d_ws, size_t ws_size,
                              hipStream_t stream) {
    const float* X  = (const float*)d_in[0];
    const float* W1 = (const float*)d_in[1];
    const float* W2 = (const float*)d_in[2];
    float* out = (float*)d_out;

    const size_t s_s1 = (size_t)NN * TT * HH * 2;   // 65,536,000
    const size_t s_Xb = (size_t)NN * TT * II * 2;   // 16,384,000
    const size_t s_W  = (size_t)HH * II * 2;        //    524,288 (x2)
    const size_t s_W2 = (size_t)32 * HH * 2;        //     65,536 (x2)
    // + y2 4,096,000 => ~87 MB total

    char* w = (char*)d_ws;
    f16*   s1b = (f16*)w;  w += s_s1;
    f16*   Xb  = (f16*)w;  w += s_Xb;
    f16*   W1h = (f16*)w;  w += s_W;
    f16*   W1l = (f16*)w;  w += s_W;
    f16*   W2h = (f16*)w;  w += s_W2;
    f16*   W2l = (f16*)w;  w += s_W2;
    float* y2  = (float*)w;

    prep_all<<<3200, 256, 0, stream>>>(X, W1, W2, Xb, W1h, W1l, W2h, W2l);

    gemm1_scan1<<<dim3(8, NN), 512, 0, stream>>>(Xb, W1h, W1l, s1b);

    gemm2_mfma<<<(NN * TT) / 64, 256, 0, stream>>>(s1b, W2h, W2l, y2);
    scan2_k<<<NN, 256, 0, stream>>>(y2, out);
}

// Round 4
// 187.653 us; speedup vs baseline: 1.4923x; 1.0716x over previous
//
#include <hip/hip_runtime.h>

// SNN forward: [merged preps] -> [GEMM1+scan1 fused, 128x128, ring-3 LDS
// counted-vmcnt K-loop, 512 thr / 8 waves] -> GEMM2 (64-row, ring-5 depth-4)
// -> scan2 (single-phase LDS, static ring).
// f16 split-2: W = hi + lo (both f16), residual ~2^-24 => fp32-grade MFMA.
// R4 ledger: {full-drain dbuf, ring-3 swizzled, direct-reg, dual-region
// interleave} -> {67, 68, 131, 81} us. 2 blocks/CU co-residency is the
// dominant term for gemm1; revert to ring-3 (R1). gemm2 was depth-2
// latency-bound (~590 cyc exposed stall/kk) -> ring-5 depth-4 (~280).

#define NN 64
#define II 256
#define HH 1024
#define OO 18
#define TT 500

#define D_SR 0.9048374180359595f   // exp(-1/10)
#define C_SR 0.27182818284590454f  // e/10
#define D_RF 0.36787944117144233f  // exp(-1)
#define C_RF 2.718281828459045f    // e
#define THETA 10.0f
#define REFS (-20.0f)

typedef _Float16 f16;
typedef _Float16 f16x8 __attribute__((ext_vector_type(8)));
typedef float f32x4 __attribute__((ext_vector_type(4)));

__device__ __forceinline__ void gl2lds16(const void* g, void* l) {
    __builtin_amdgcn_global_load_lds(
        (const __attribute__((address_space(1))) void*)g,
        (__attribute__((address_space(3))) void*)l, 16, 0, 0);
}

// ---------------- merged prep: X transpose + W1 hi/lo + W2 hi/lo ------------
// grid 3200: [0,2048) prep_x tiles, [2048,3072) W1, [3072,3200) W2.
__launch_bounds__(256)
__global__ void prep_all(const float* __restrict__ X, const float* __restrict__ W1,
                         const float* __restrict__ W2, f16* __restrict__ Xb,
                         f16* __restrict__ W1h, f16* __restrict__ W1l,
                         f16* __restrict__ W2h, f16* __restrict__ W2l) {
    __shared__ float tile[64][65];
    const int b = blockIdx.x;
    const int tid = threadIdx.x;

    if (b < 2048) {
        const int t0 = (b & 7) * 64, i0 = ((b >> 3) & 3) * 64, n = b >> 5;
        const int tx = tid & 63, q = tid >> 6;
        const float* Xn = X + (size_t)n * II * TT;
#pragma unroll 4
        for (int j = 0; j < 16; ++j) {
            int il = j * 4 + q;
            int t = t0 + tx;
            tile[il][tx] = (t < TT) ? Xn[(size_t)(i0 + il) * TT + t] : 0.f;
        }
        __syncthreads();
#pragma unroll 4
        for (int j = 0; j < 16; ++j) {
            int tl = j * 4 + q;
            int t = t0 + tl;
            if (t < TT)
                Xb[((size_t)n * TT + t) * II + i0 + tx] = (f16)tile[tx][tl];
        }
    } else if (b < 3072) {
        int idx = (b - 2048) * 256 + tid;
        float w = W1[idx];
        f16 h = (f16)w;
        f16 l = (f16)(w - (float)h);
        W1h[idx] = h;
        W1l[idx] = l;
    } else {
        int idx = (b - 3072) * 256 + tid;
        int o = idx >> 10;
        float w = (o < OO) ? W2[idx] : 0.f;
        f16 h = (f16)w;
        f16 l = (f16)(w - (float)h);
        W2h[idx] = h;
        W2l[idx] = l;
    }
}

// ---------------- FUSED layer 1: 128x128 tile, ring-3 K-loop, 8 waves ------
// grid (8, 64), 512 thr. Per block: 4 t-chunks of 128.
// Wave layout 2m x 4n. Staging: wave w stages rows [w*16, w*16+16).
// LDS swizzle: physical 16B slot p of row r holds logical slot p ^ ((r>>1)&3)
// => applied to SOURCE k-offset at stage, and to read addr. 2-way max (free).
__launch_bounds__(512)
__global__ void gemm1_scan1(const f16* __restrict__ Xb, const f16* __restrict__ Wh,
                            const f16* __restrict__ Wl, f16* __restrict__ S1) {
    __shared__ __align__(16) char smem[3 * 24576];  // 73,728 B (yb uses 67,584)
    float* yb = (float*)smem;

    const int tid = threadIdx.x;
    const int wave = tid >> 6, lane = tid & 63;

    // XCD swizzle: the 8 h-tiles of one n share an XCD
    const int f = blockIdx.y * 8 + blockIdx.x;
    const int x = f & 7, g = f >> 3;
    const int n = x * 8 + (g & 7);
    const int ht = g >> 3;
    const int h0g = ht * 128;

    const int rbl = wave * 16 + (lane >> 2);   // staged row 0..127
    // swizzled source slot: (lane&3) ^ sigma(row), sigma(row)=(lane>>3)&3
    const int koff = (((lane & 3) ^ ((lane >> 3) & 3))) * 8;
    const f16* gBh0 = Wh + (size_t)(h0g + rbl) * II + koff;
    const f16* gBl0 = Wl + (size_t)(h0g + rbl) * II + koff;

    const int wm = wave & 1, wn = wave >> 1;   // 2m x 4n
    const int fr = lane & 15, kq = lane >> 4;
    const int kz = (kq ^ ((fr >> 1) & 3)) * 8;  // swizzled read slot (f16 idx)

    float p1 = 0.f, a1 = 0.f, p2 = 0.f, a2 = 0.f;  // scan state (tid<128)

    for (int c = 0; c < 4; ++c) {
        const int t0 = c * 128;
        const int TCe = (TT - t0 < 128) ? (TT - t0) : 128;

        int r0 = rbl; if (r0 > TCe - 1) r0 = TCe - 1;
        const f16* gA0 = Xb + ((size_t)n * TT + t0 + r0) * II + koff;

        auto stage = [&](int kk2, int b) {
            f16* As_b = (f16*)(smem + b * 24576);
            f16* Bh_b = As_b + 4096;   // f16 elements: As = 128*32 = 4096
            f16* Bl_b = As_b + 8192;
            const int ko = kk2 * 32;
            gl2lds16(gA0 + ko, As_b + wave * 512);
            gl2lds16(gBh0 + ko, Bh_b + wave * 512);
            gl2lds16(gBl0 + ko, Bl_b + wave * 512);
        };

        // prologue: prev chunk's post-scan barrier protects buf0/buf1 (yb)
        stage(0, 0);
        stage(1, 1);

        f32x4 acc[4][2] = {};
#pragma unroll
        for (int kk = 0; kk < 8; ++kk) {
            // buf[kk%3] DMA done when only the newest stage (3 loads) is
            // outstanding; vmcnt retires in order (m135).
            if (kk < 7) asm volatile("s_waitcnt vmcnt(3)" ::: "memory");
            else        asm volatile("s_waitcnt vmcnt(0)" ::: "memory");
            __builtin_amdgcn_s_barrier();
            __builtin_amdgcn_sched_barrier(0);
            if (kk < 6) stage(kk + 2, (kk + 2) % 3);

            const f16* As_b = (const f16*)(smem + (kk % 3) * 24576);
            const f16* Bh_b = As_b + 4096;
            const f16* Bl_b = As_b + 8192;

            f16x8 av[4], bhv[2], blv[2];
#pragma unroll
            for (int i = 0; i < 4; ++i)
                av[i] = *(const f16x8*)(As_b + (wm * 64 + i * 16 + fr) * 32 + kz);
#pragma unroll
            for (int j = 0; j < 2; ++j) {
                bhv[j] = *(const f16x8*)(Bh_b + (wn * 32 + j * 16 + fr) * 32 + kz);
                blv[j] = *(const f16x8*)(Bl_b + (wn * 32 + j * 16 + fr) * 32 + kz);
            }
            __builtin_amdgcn_s_setprio(1);
#pragma unroll
            for (int i = 0; i < 4; ++i)
#pragma unroll
                for (int j = 0; j < 2; ++j) {
                    acc[i][j] = __builtin_amdgcn_mfma_f32_16x16x32_f16(av[i], bhv[j], acc[i][j], 0, 0, 0);
                    acc[i][j] = __builtin_amdgcn_mfma_f32_16x16x32_f16(av[i], blv[j], acc[i][j], 0, 0, 0);
                }
            __builtin_amdgcn_s_setprio(0);
        }
        __syncthreads();  // all frag reads done before epilogue overwrites staging

        // epilogue: acc -> yb (t-major, stride 132)
#pragma unroll
        for (int i = 0; i < 4; ++i)
#pragma unroll
            for (int j = 0; j < 2; ++j) {
                int tr = wm * 64 + i * 16 + kq * 4;
                int hc = wn * 32 + j * 16 + fr;
#pragma unroll
                for (int r = 0; r < 4; ++r)
                    yb[(tr + r) * 132 + hc] = acc[i][j][r];
            }
        __syncthreads();

        // sequential scan (waves 0-1); 8-deep ring; spikes -> global directly
        if (tid < 128) {
            f16* sq = S1 + ((size_t)n * TT + t0) * HH + h0g + tid;
            float rb_[8];
#pragma unroll
            for (int j = 0; j < 8; ++j) rb_[j] = yb[j * 132 + tid];
            int t = 0;
            for (; t + 8 <= TCe; t += 8) {
#pragma unroll
                for (int j = 0; j < 8; ++j) {
                    float xv = rb_[j];
                    int tn = t + j + 8;
                    rb_[j] = (tn < TCe) ? yb[tn * 132 + tid] : 0.f;
                    a1 = D_SR * (a1 + p1);
                    p1 = D_SR * p1 + xv;
                    float ut = C_SR * a1;
                    a2 = D_RF * (a2 + p2);
                    float u = ut + C_RF * a2;
                    float s = (u >= THETA) ? 1.0f : 0.0f;
                    p2 = D_RF * p2 + REFS * s;
                    sq[(size_t)(t + j) * HH] = (f16)s;
                }
            }
            int rem = TCe - t;
#pragma unroll
            for (int j = 0; j < 8; ++j) {
                if (j < rem) {
                    float xv = rb_[j];
                    a1 = D_SR * (a1 + p1);
                    p1 = D_SR * p1 + xv;
                    float ut = C_SR * a1;
                    a2 = D_RF * (a2 + p2);
                    float u = ut + C_RF * a2;
                    float s = (u >= THETA) ? 1.0f : 0.0f;
                    p2 = D_RF * p2 + REFS * s;
                    sq[(size_t)(t + j) * HH] = (f16)s;
                }
            }
        }
        __syncthreads();  // yb reads done; next chunk's staging may overwrite
    }
}

// ---------------- GEMM2 (MFMA, split-f16, ring-5 depth-4, 64-row tiles) -----
// grid 500; 256 thr; tile 64 m x 32 o; K=1024, BK=32.
// Depth-2 was latency-bound: ~155 cyc MFMA/SIMD/kk vs ~900 cyc DMA latency
// => ~590 cyc exposed per kk. Depth-4 (vmcnt(6) steady) cuts that to ~280.
__launch_bounds__(256)
__global__ void gemm2_mfma(const f16* __restrict__ S1, const f16* __restrict__ W2h,
                           const f16* __restrict__ W2l, float* __restrict__ Y2) {
    __shared__ __align__(16) f16 As[5][64 * 32];  // 5 x 4 KB
    __shared__ __align__(16) f16 Bh[5][32 * 32];  // 5 x 2 KB
    __shared__ __align__(16) f16 Bl[5][32 * 32];  // 5 x 2 KB

    const int tid = threadIdx.x;
    const int wave = tid >> 6, lane = tid & 63;
    const int m0 = blockIdx.x * 64;
    const int fr = lane & 15, kq = lane >> 4;
    const int koff = (((lane & 3) ^ ((lane >> 3) & 3))) * 8;  // swizzled src slot
    const int kz = (kq ^ ((fr >> 1) & 3)) * 8;                // swizzled read slot

    const f16* gA = S1 + (size_t)(m0 + wave * 16 + (lane >> 2)) * HH + koff;
    const f16* gB = (wave < 2 ? W2h : W2l) + (size_t)((wave & 1) * 16 + (lane >> 2)) * HH + koff;

    auto stage = [&](int kk2, int b) {
        const int ko = kk2 * 32;
        gl2lds16(gA + ko, &As[b][wave * 512]);
        gl2lds16(gB + ko, (wave < 2 ? &Bh[b][0] : &Bl[b][0]) + (wave & 1) * 512);
    };

    stage(0, 0);
    stage(1, 1);
    stage(2, 2);
    stage(3, 3);

    f32x4 acc[2] = {};
#pragma unroll
    for (int kk = 0; kk < HH / 32; ++kk) {
        // steady: 3 newer stages (6 loads) may stay in flight; tail drains.
        if (kk <= HH / 32 - 4)      asm volatile("s_waitcnt vmcnt(6)" ::: "memory");
        else if (kk == HH / 32 - 3) asm volatile("s_waitcnt vmcnt(4)" ::: "memory");
        else if (kk == HH / 32 - 2) asm volatile("s_waitcnt vmcnt(2)" ::: "memory");
        else                        asm volatile("s_waitcnt vmcnt(0)" ::: "memory");
        __builtin_amdgcn_s_barrier();
        __builtin_amdgcn_sched_barrier(0);
        if (kk < HH / 32 - 4) stage(kk + 4, (kk + 4) % 5);
        const int b = kk % 5;

        f16x8 a, bh[2], bl[2];
        a = *(const f16x8*)(&As[b][(wave * 16 + fr) * 32 + kz]);
#pragma unroll
        for (int j = 0; j < 2; ++j) {
            bh[j] = *(const f16x8*)(&Bh[b][(j * 16 + fr) * 32 + kz]);
            bl[j] = *(const f16x8*)(&Bl[b][(j * 16 + fr) * 32 + kz]);
        }
        __builtin_amdgcn_s_setprio(1);
#pragma unroll
        for (int j = 0; j < 2; ++j) {
            acc[j] = __builtin_amdgcn_mfma_f32_16x16x32_f16(a, bh[j], acc[j], 0, 0, 0);
            acc[j] = __builtin_amdgcn_mfma_f32_16x16x32_f16(a, bl[j], acc[j], 0, 0, 0);
        }
        __builtin_amdgcn_s_setprio(0);
    }

#pragma unroll
    for (int j = 0; j < 2; ++j) {
        int rbase = m0 + wave * 16 + kq * 4;
        int cc = j * 16 + fr;
        float* p = Y2 + (size_t)rbase * 32 + cc;
#pragma unroll
        for (int r = 0; r < 4; ++r)
            p[(size_t)r * 32] = acc[j][r];
    }
}

// ---------------- scan2: single-phase LDS, static-index ring ----------------
__launch_bounds__(256)
__global__ void scan2_k(const float* __restrict__ Y2, float* __restrict__ Out) {
    __shared__ float yc[TT * 32];    // 64,000 B
    __shared__ float sb[OO * TT];    // 36,000 B
    const int n = blockIdx.x, tid = threadIdx.x;

    const float4* src = (const float4*)(Y2 + (size_t)n * TT * 32);
    float4* dst = (float4*)yc;
    for (int i = tid; i < TT * 8; i += 256) dst[i] = src[i];
    __syncthreads();

    if (tid < 32) {
        float p1 = 0.f, a1 = 0.f, p2 = 0.f, a2 = 0.f;
        float rb_[8];
#pragma unroll
        for (int j = 0; j < 8; ++j) rb_[j] = yc[j * 32 + tid];
        int t = 0;
        for (; t + 8 <= TT; t += 8) {
#pragma unroll
            for (int j = 0; j < 8; ++j) {
                float xv = rb_[j];
                int tn = t + j + 8;
                rb_[j] = (tn < TT) ? yc[tn * 32 + tid] : 0.f;
                a1 = D_SR * (a1 + p1);
                p1 = D_SR * p1 + xv;
                float ut = C_SR * a1;
                a2 = D_RF * (a2 + p2);
                float u = ut + C_RF * a2;
                float s = (u >= THETA) ? 1.0f : 0.0f;
                p2 = D_RF * p2 + REFS * s;
                if (tid < OO) sb[tid * TT + t + j] = s;
            }
        }
#pragma unroll
        for (int j = 0; j < 8; ++j) {
            if (t + j < TT) {
                float xv = rb_[j];
                a1 = D_SR * (a1 + p1);
                p1 = D_SR * p1 + xv;
                float ut = C_SR * a1;
                a2 = D_RF * (a2 + p2);
                float u = ut + C_RF * a2;
                float s = (u >= THETA) ? 1.0f : 0.0f;
                p2 = D_RF * p2 + REFS * s;
                if (tid < OO) sb[tid * TT + t + j] = s;
            }
        }
    }
    __syncthreads();

    float* on = Out + (size_t)n * OO * TT;
    for (int e = tid; e < OO * TT; e += 256) on[e] = sb[e];
}

extern "C" void kernel_launch(void* const* d_in, const int* in_sizes, int n_in,
                              void* d_out, int out_size, void* d_ws, size_t ws_size,
                              hipStream_t stream) {
    const float* X  = (const float*)d_in[0];
    const float* W1 = (const float*)d_in[1];
    const float* W2 = (const float*)d_in[2];
    float* out = (float*)d_out;

    const size_t s_s1 = (size_t)NN * TT * HH * 2;   // 65,536,000
    const size_t s_Xb = (size_t)NN * TT * II * 2;   // 16,384,000
    const size_t s_W  = (size_t)HH * II * 2;        //    524,288 (x2)
    const size_t s_W2 = (size_t)32 * HH * 2;        //     65,536 (x2)
    // + y2 4,096,000 => ~87 MB total

    char* w = (char*)d_ws;
    f16*   s1b = (f16*)w;  w += s_s1;
    f16*   Xb  = (f16*)w;  w += s_Xb;
    f16*   W1h = (f16*)w;  w += s_W;
    f16*   W1l = (f16*)w;  w += s_W;
    f16*   W2h = (f16*)w;  w += s_W2;
    f16*   W2l = (f16*)w;  w += s_W2;
    float* y2  = (float*)w;

    prep_all<<<3200, 256, 0, stream>>>(X, W1, W2, Xb, W1h, W1l, W2h, W2l);

    gemm1_scan1<<<dim3(8, NN), 512, 0, stream>>>(Xb, W1h, W1l, s1b);

    gemm2_mfma<<<(NN * TT) / 64, 256, 0, stream>>>(s1b, W2h, W2l, y2);
    scan2_k<<<NN, 256, 0, stream>>>(y2, out);
}